// Round 1
// baseline (307.144 us; speedup 1.0000x reference)
//
#include <hip/hip_runtime.h>

// AttentionFusion: fused = sigmoid(x1.w - x2.w)*x1 + (1-sig)*x2, per row.
// N=16384 rows, D=2048 cols, fp32. One block per row, 256 threads.
// Single-pass: rows of x1/x2 stay in registers between dot and fuse.

#define NROWS 16384
#define DCOLS 2048

__global__ __launch_bounds__(256) void attn_fuse_kernel(
    const float* __restrict__ x1,
    const float* __restrict__ x2,
    const float* __restrict__ w,
    float* __restrict__ fused,
    float* __restrict__ alpha)
{
    const int row = blockIdx.x;
    const int t = threadIdx.x;

    const float4* x1v = (const float4*)(x1 + (size_t)row * DCOLS);
    const float4* x2v = (const float4*)(x2 + (size_t)row * DCOLS);
    const float4* wv  = (const float4*)w;

    // 512 float4s per row, 256 threads -> 2 per thread (coalesced).
    float4 a0 = x1v[t];
    float4 a1 = x1v[t + 256];
    float4 b0 = x2v[t];
    float4 b1 = x2v[t + 256];
    float4 w0 = wv[t];
    float4 w1 = wv[t + 256];

    // Partial of dot(x1 - x2, w): only the score difference matters.
    float p = (a0.x - b0.x) * w0.x + (a0.y - b0.y) * w0.y
            + (a0.z - b0.z) * w0.z + (a0.w - b0.w) * w0.w
            + (a1.x - b1.x) * w1.x + (a1.y - b1.y) * w1.y
            + (a1.z - b1.z) * w1.z + (a1.w - b1.w) * w1.w;

    // Wave-64 butterfly-style reduce.
    #pragma unroll
    for (int off = 32; off > 0; off >>= 1)
        p += __shfl_down(p, off, 64);

    // Cross-wave (4 waves) reduce via LDS, broadcast to all threads.
    __shared__ float wave_sum[4];
    const int wave = t >> 6;
    const int lane = t & 63;
    if (lane == 0) wave_sum[wave] = p;
    __syncthreads();
    const float d = wave_sum[0] + wave_sum[1] + wave_sum[2] + wave_sum[3];

    const float a1g = 1.0f / (1.0f + expf(-d));  // alpha1 = sigmoid(s1 - s2)

    // fused = x2 + alpha1*(x1 - x2), from registers (no global re-read).
    float4 f0, f1;
    f0.x = b0.x + a1g * (a0.x - b0.x);
    f0.y = b0.y + a1g * (a0.y - b0.y);
    f0.z = b0.z + a1g * (a0.z - b0.z);
    f0.w = b0.w + a1g * (a0.w - b0.w);
    f1.x = b1.x + a1g * (a1.x - b1.x);
    f1.y = b1.y + a1g * (a1.y - b1.y);
    f1.z = b1.z + a1g * (a1.z - b1.z);
    f1.w = b1.w + a1g * (a1.w - b1.w);

    float4* outv = (float4*)(fused + (size_t)row * DCOLS);
    outv[t] = f0;
    outv[t + 256] = f1;

    if (t == 0) {
        alpha[(size_t)row * 2]     = a1g;
        alpha[(size_t)row * 2 + 1] = 1.0f - a1g;
    }
}

extern "C" void kernel_launch(void* const* d_in, const int* in_sizes, int n_in,
                              void* d_out, int out_size, void* d_ws, size_t ws_size,
                              hipStream_t stream)
{
    const float* x1 = (const float*)d_in[0];
    const float* x2 = (const float*)d_in[1];
    const float* w  = (const float*)d_in[2];

    float* fused = (float*)d_out;                       // [N, D]
    float* alpha = fused + (size_t)NROWS * DCOLS;       // [N, 2]

    attn_fuse_kernel<<<NROWS, 256, 0, stream>>>(x1, x2, w, fused, alpha);
}